// Round 11
// baseline (601.297 us; speedup 1.0000x reference)
//
#include <hip/hip_runtime.h>
#include <cstdint>

typedef unsigned short u16;

constexpr int BATCH = 128;
constexpr int H = 512, W = 512;
constexpr int HW = H * W;       // 2^18
constexpr int WPR = W / 64;     // 8 words per row
constexpr int WPI = HW / 64;    // 4096 words per image
constexpr int NSEED = 1000;
constexpr int MARGIN = 3000;    // expected candidate count for threshold select
constexpr int CAP2 = 4096;      // per-image candidate list capacity
constexpr int CAPS = 1024;      // tie list capacity (mean ~64)
constexpr int LBUF = 2048;      // per-block LDS candidate buffer
constexpr int NBIN = 4096;      // gh stride; bins 0..4079 used (g = floor(v*4080))
constexpr int QSEG = 256;       // per-wave ring: drain-128 -> carry<128 + append<=64

// ---------------- Threefry-2x32 (20 rounds), bit-exact vs JAX ----------------
__device__ __forceinline__ uint32_t rotl32(uint32_t v, int d) {
  return (v << d) | (v >> (32 - d));
}

__device__ __forceinline__ void tf2x32(uint32_t k0, uint32_t k1,
                                       uint32_t x0, uint32_t x1,
                                       uint32_t &o0, uint32_t &o1) {
  uint32_t ks2 = k0 ^ k1 ^ 0x1BD11BDAu;
  x0 += k0; x1 += k1;
  x0 += x1; x1 = rotl32(x1, 13); x1 ^= x0;
  x0 += x1; x1 = rotl32(x1, 15); x1 ^= x0;
  x0 += x1; x1 = rotl32(x1, 26); x1 ^= x0;
  x0 += x1; x1 = rotl32(x1, 6);  x1 ^= x0;
  x0 += k1; x1 += ks2 + 1u;
  x0 += x1; x1 = rotl32(x1, 17); x1 ^= x0;
  x0 += x1; x1 = rotl32(x1, 29); x1 ^= x0;
  x0 += x1; x1 = rotl32(x1, 16); x1 ^= x0;
  x0 += x1; x1 = rotl32(x1, 24); x1 ^= x0;
  x0 += ks2; x1 += k0 + 2u;
  x0 += x1; x1 = rotl32(x1, 13); x1 ^= x0;
  x0 += x1; x1 = rotl32(x1, 15); x1 ^= x0;
  x0 += x1; x1 = rotl32(x1, 26); x1 ^= x0;
  x0 += x1; x1 = rotl32(x1, 6);  x1 ^= x0;
  x0 += k0; x1 += k1 + 3u;
  x0 += x1; x1 = rotl32(x1, 17); x1 ^= x0;
  x0 += x1; x1 = rotl32(x1, 29); x1 ^= x0;
  x0 += x1; x1 = rotl32(x1, 16); x1 ^= x0;
  x0 += x1; x1 = rotl32(x1, 24); x1 ^= x0;
  x0 += k1; x1 += ks2 + 4u;
  x0 += x1; x1 = rotl32(x1, 13); x1 ^= x0;
  x0 += x1; x1 = rotl32(x1, 15); x1 ^= x0;
  x0 += x1; x1 = rotl32(x1, 26); x1 ^= x0;
  x0 += x1; x1 = rotl32(x1, 6);  x1 ^= x0;
  x0 += ks2; x1 += k0 + 5u;
  o0 = x0; o1 = x1;
}

__device__ __forceinline__ uint32_t score_bits(uint32_t k0, uint32_t k1, uint32_t i) {
  uint32_t a, c; tf2x32(k0, k1, 0u, i, a, c);
  return a ^ c;
}

// ---------------- per-image keys + nbr_bg + bg score threshold ----------------
__device__ __forceinline__ void keygen(int b, uint32_t* keys, uint32_t* kbg,
                                       uint32_t* Tbg) {
  uint32_t kb0, kb1; tf2x32(0u, 42u, 0u, (uint32_t)b, kb0, kb1);
  uint32_t kf0, kf1; tf2x32(kb0, kb1, 0u, 0u, kf0, kf1);
  uint32_t kB0, kB1; tf2x32(kb0, kb1, 0u, 1u, kB0, kB1);
  uint32_t kz0, kz1; tf2x32(kb0, kb1, 0u, 2u, kz0, kz1);
  uint32_t za, zc; tf2x32(kz0, kz1, 0u, 0u, za, zc);
  uint32_t zb = za ^ zc;
  keys[b * 4 + 0] = kf0; keys[b * 4 + 1] = kf1;
  keys[b * 4 + 2] = kB0; keys[b * 4 + 3] = kB1;
  float uu = __uint_as_float((zb >> 9) | 0x3f800000u) - 1.0f;
  float span = __fsub_rn(0.7f, 0.3f);
  float z = __fadd_rn(__fmul_rn(uu, span), 0.3f);
  z = fmaxf(0.3f, z);
  float nb = ceilf(__fmul_rn(z, (float)HW));
  uint32_t K = (uint32_t)nb;
  kbg[b] = K;
  float tv = floorf((1.0f - (float)MARGIN / (float)K) * 8388608.0f);
  Tbg[b] = (uint32_t)fmaxf(tv, 0.0f);
}

// ---- paired Otsu cumsum: count+mass trees in ONE 17-barrier pass. ----
__device__ __forceinline__ void lds_tree_cumsum256x2(float* Lc, float* Sc,
                                                     float* Lm, float* Sm, int tid) {
  const int off[9] = {0, 256, 384, 448, 480, 496, 504, 508, 510};
  const int sz[9]  = {256, 128, 64, 32, 16, 8, 4, 2, 1};
  for (int l = 0; l < 8; ++l) {
    int o = off[l], on = off[l + 1], n = sz[l + 1];
    if (tid < n) {
      Lc[on + tid] = __fadd_rn(Lc[o + 2 * tid], Lc[o + 2 * tid + 1]);
      Lm[on + tid] = __fadd_rn(Lm[o + 2 * tid], Lm[o + 2 * tid + 1]);
    }
    __syncthreads();
  }
  if (tid == 0) { Sc[off[8]] = Lc[off[8]]; Sm[off[8]] = Lm[off[8]]; }
  __syncthreads();
  for (int l = 7; l >= 0; --l) {
    int o = off[l], on = off[l + 1], hn = sz[l] / 2;
    if (tid == 0) { Sc[o] = Lc[o]; Sm[o] = Lm[o]; }
    if (tid < hn) { Sc[o + 2 * tid + 1] = Sc[on + tid]; Sm[o + 2 * tid + 1] = Sm[on + tid]; }
    if (tid >= 1 && tid < hn) {
      Sc[o + 2 * tid] = __fadd_rn(Sc[on + tid - 1], Lc[o + 2 * tid]);
      Sm[o + 2 * tid] = __fadd_rn(Sm[on + tid - 1], Lm[o + 2 * tid]);
    }
    __syncthreads();
  }
}

// -------- fused x sweep + keygen (per-image) + LAST-BLOCK-DONE Otsu/K-scan.
//          The 4th finishing block per image runs the full 1024-thread Otsu
//          (r6-verified compressed code) using device-scope fence+atomic. ----
__global__ __launch_bounds__(1024) void k_binify(const float4* __restrict__ x4,
                                                 u16* __restrict__ g,
                                                 uint32_t* __restrict__ gh,
                                                 uint32_t* __restrict__ keys,
                                                 uint32_t* __restrict__ kbg,
                                                 uint32_t* __restrict__ Tbg,
                                                 uint32_t* __restrict__ done,
                                                 int* __restrict__ th_out,
                                                 uint32_t* __restrict__ b1a,
                                                 uint32_t* __restrict__ r1a) {
  __shared__ uint32_t h[NBIN];
  __shared__ float Lc[511], Sc[511], Lm[511], Sm[511];
  __shared__ float av[4];
  __shared__ int ai[4];
  __shared__ uint32_t amLast;
  int b = blockIdx.x >> 2, sub = blockIdx.x & 3, t = threadIdx.x;
  if (sub == 0 && t == 0) keygen(b, keys, kbg, Tbg);   // ordered via done-group
  for (int i = t; i < NBIN; i += 1024) h[i] = 0;
  __syncthreads();
  const float4* xb = x4 + ((size_t)b * HW + (size_t)sub * (HW / 4)) / 4;
  ushort4* gb4 = (ushort4*)g + ((size_t)b * HW + (size_t)sub * (HW / 4)) / 4;
  for (int i = t; i < HW / 16; i += 1024) {
    float4 v4 = xb[i];
    int g0 = (int)floorf(__fmul_rn(v4.x, 4080.0f)); g0 = min(max(g0, 0), 4079);
    int g1 = (int)floorf(__fmul_rn(v4.y, 4080.0f)); g1 = min(max(g1, 0), 4079);
    int g2 = (int)floorf(__fmul_rn(v4.z, 4080.0f)); g2 = min(max(g2, 0), 4079);
    int g3 = (int)floorf(__fmul_rn(v4.w, 4080.0f)); g3 = min(max(g3, 0), 4079);
    atomicAdd(&h[g0], 1u);
    atomicAdd(&h[g1], 1u);
    atomicAdd(&h[g2], 1u);
    atomicAdd(&h[g3], 1u);
    ushort4 o;
    o.x = (u16)g0; o.y = (u16)g1; o.z = (u16)g2; o.w = (u16)g3;
    gb4[i] = o;
  }
  __syncthreads();
  uint32_t* dst = gh + ((size_t)blockIdx.x << 12);   // per-(b,sub) histogram
  for (int i = t; i < NBIN; i += 1024) dst[i] = h[i];
  // ---- release: all gh/g/key stores visible device-wide, then arrive ----
  __threadfence();
  __syncthreads();
  if (t == 0) amLast = (atomicAdd(&done[b], 1u) == 3u) ? 1u : 0u;
  __syncthreads();
  if (!amLast) return;
  __threadfence();   // acquire side
  // ---------- Otsu threshold + ascending-K scan (1024 threads) ----------
  {
    const uint32_t* g0 = gh + ((size_t)(b * 4 + 0) << 12);
    const uint32_t* g1 = gh + ((size_t)(b * 4 + 1) << 12);
    const uint32_t* g2 = gh + ((size_t)(b * 4 + 2) << 12);
    const uint32_t* g3 = gh + ((size_t)(b * 4 + 3) << 12);
    for (int i = t; i < NBIN; i += 1024) h[i] = g0[i] + g1[i] + g2[i] + g3[i];
    __syncthreads();
    if (t < 256) {
      uint32_t hv = 0;
#pragma unroll
      for (int i = 0; i < 16; ++i) hv += h[t * 16 + ((i + t) & 15)];  // rotated
      Lc[t] = (float)hv;
      Lm[t] = __fmul_rn((float)hv, (float)t);
    }
    __syncthreads();
    lds_tree_cumsum256x2(Lc, Sc, Lm, Sm, t);   // 17 barriers
    uint32_t K = kbg[b];
    if (t < 256) {
      float total = (float)HW;
      float mT = Sm[255];
      float w = Sc[t];
      float denom = __fmul_rn(w, __fsub_rn(total, w));
      float s = 0.0f;
      if (denom > 0.0f) {
        float d  = __fsub_rn(__fmul_rn(mT, w), __fmul_rn(total, Sm[t]));
        float nu = __fmul_rn(d, d);
        float dd = __fmul_rn(__fmul_rn(denom, total), total);
        s = __fdiv_rn(nu, dd);
      }
      float bv = s; int bidx = t;
#pragma unroll
      for (int d = 32; d >= 1; d >>= 1) {
        float ov = __shfl_xor(bv, d, 64);
        int oi = __shfl_xor(bidx, d, 64);
        if (ov > bv || (ov == bv && oi < bidx)) { bv = ov; bidx = oi; }
      }
      if ((t & 63) == 0) { av[t >> 6] = bv; ai[t >> 6] = bidx; }
      bool gf = (Sc[t] >= (float)K) && (t == 0 || Sc[t - 1] < (float)K);
      if (gf) {   // exactly one thread; 16-bin inner scan
        uint32_t accv = (t == 0) ? 0u : (uint32_t)Sc[t - 1];
        uint32_t b1v = 0, r1v = 1;
        for (int bin = t * 16; bin < t * 16 + 16; ++bin) {
          uint32_t cc = h[bin];
          if (accv + cc >= K) { b1v = (uint32_t)bin; r1v = K - accv; break; }
          accv += cc;
        }
        b1a[b] = b1v; r1a[b] = r1v;
      }
    }
    __syncthreads();
    if (t == 0) {
      float bv = av[0]; int bidx = ai[0];
#pragma unroll
      for (int wv = 1; wv < 4; ++wv) {
        float ov = av[wv]; int oi = ai[wv];
        if (ov > bv || (ov == bv && oi < bidx)) { bv = ov; bidx = oi; }
      }
      int bi = bidx;
      if (bi == 0) bi = 1;
      if (bi == 255) bi = 254;
      th_out[b] = bi;
    }
  }
}

// ==== mega-fused lean body: ROI bits + 11x11 erosion + E count + bg
//      candidates. Drain-128 + next-row load prefetch. ====
__global__ __launch_bounds__(1024) void k_main(const u16* __restrict__ gq,
                                               const float* __restrict__ x,
                                               const int* __restrict__ th,
                                               const uint32_t* __restrict__ b1a,
                                               const uint32_t* __restrict__ Tbg,
                                               const uint32_t* __restrict__ keys,
                                               uint32_t* __restrict__ Efg,
                                               uint32_t* __restrict__ cnt_bg,
                                               uint64_t* __restrict__ list,
                                               uint32_t* __restrict__ cnt_be,
                                               uint64_t* __restrict__ list_be,
                                               uint64_t* __restrict__ erod) {
  __shared__ uint64_t sroi[1104];      // roi bits, slab rows (<=138) x 8 words
  __shared__ uint64_t srow[1104];      // after 11-wide row min
  __shared__ uint64_t lbuf[LBUF];      // candidate keys
  __shared__ uint32_t wq[16 * QSEG];   // per-wave eligible rings (16 KB)
  __shared__ uint32_t lcnt, gbase;
  int b = blockIdx.x >> 2, sub = blockIdx.x & 3, t = threadIdx.x;
  int wave = t >> 6, lane = t & 63;
  int R0 = sub * 128;
  int rlo = max(R0 - 5, 0), rhi = min(R0 + 133, H);
  int nwords = (rhi - rlo) * 8;
  const u16* gb = gq + (size_t)b * HW;
  const float* xb = x + (size_t)b * HW;
  int groi = (th[b] + 1) << 4;     // g >= 16*(th+1)  <=>  floor(v*255) > th
  uint32_t b1 = b1a[b];
  uint32_t T = Tbg[b];
  uint32_t k0 = keys[b * 4 + 2], k1 = keys[b * 4 + 3];
  if (t == 0) lcnt = 0;
  __syncthreads();
  uint32_t* q = wq + wave * QSEG;
  uint32_t qlen = 0, hd = 0;
  uint64_t lmask = (1ull << lane) - 1ull;
  // phase A: wave owns 8 core rows; prefetch next row; drain-128 per column
  int absr0 = R0 + wave * 8;
  u16 gvals[8];
  {
    const u16* gp8 = gb + absr0 * W + lane;
#pragma unroll
    for (int c = 0; c < 8; ++c) gvals[c] = gp8[c * 64];
  }
  for (int r = 0; r < 8; ++r) {
    int absr = absr0 + r;
    int rowbase = absr * W + lane;
    int swbase = (absr - rlo) * 8;
    u16 gnext[8];
    if (r < 7) {
      const u16* gp8 = gb + (absr + 1) * W + lane;
#pragma unroll
      for (int c = 0; c < 8; ++c) gnext[c] = gp8[c * 64];
    }
#pragma unroll
    for (int c = 0; c < 8; ++c) {
      uint32_t gv = (uint32_t)gvals[c];
      uint64_t bw = __ballot((int)gv >= groi);
      if (lane == 0) sroi[swbase + c] = bw;
      bool elig = gv < b1;
      uint64_t m = __ballot(elig);
      if (elig) {
        uint32_t rank = (uint32_t)__popcll(m & lmask);
        uint32_t idx = hd + qlen + rank;
        if (idx >= (uint32_t)QSEG) idx -= (uint32_t)QSEG;
        q[idx] = (uint32_t)(rowbase + c * 64);
      }
      qlen += (uint32_t)__popcll(m);
      if (gv == b1) {   // rare (~64/image): boundary bin, exact-value tie
        uint32_t gp = atomicAdd(&cnt_be[b], 1u);
        if (gp < (uint32_t)CAPS)
          list_be[(size_t)b * CAPS + gp] =
              (((uint64_t)__float_as_uint(xb[rowbase + c * 64])) << 18) |
              (uint32_t)(rowbase + c * 64);
      }
      while (qlen >= 128u) {         // wave-uniform; 2 indep threefrys/lane
        __builtin_amdgcn_wave_barrier();
        uint32_t i0 = hd + (uint32_t)lane;
        if (i0 >= (uint32_t)QSEG) i0 -= (uint32_t)QSEG;
        uint32_t i1 = hd + 64u + (uint32_t)lane;
        if (i1 >= (uint32_t)QSEG) i1 -= (uint32_t)QSEG;
        uint32_t p0 = q[i0];
        uint32_t p1 = q[i1];
        hd += 128u; if (hd >= (uint32_t)QSEG) hd -= (uint32_t)QSEG;
        qlen -= 128u;
        uint32_t v0 = score_bits(k0, k1, p0) >> 9;
        uint32_t v1 = score_bits(k0, k1, p1) >> 9;
        if (v0 >= T) {
          uint32_t pos = atomicAdd(&lcnt, 1u);
          uint64_t key = (((uint64_t)((~v0) & 0x7FFFFFu)) << 18) | p0;
          if (pos < (uint32_t)LBUF) lbuf[pos] = key;
          else { uint32_t gp = atomicAdd(&cnt_bg[b], 1u);
                 if (gp < (uint32_t)CAP2) list[(size_t)b * CAP2 + gp] = key; }
        }
        if (v1 >= T) {
          uint32_t pos = atomicAdd(&lcnt, 1u);
          uint64_t key = (((uint64_t)((~v1) & 0x7FFFFFu)) << 18) | p1;
          if (pos < (uint32_t)LBUF) lbuf[pos] = key;
          else { uint32_t gp = atomicAdd(&cnt_bg[b], 1u);
                 if (gp < (uint32_t)CAP2) list[(size_t)b * CAP2 + gp] = key; }
        }
      }
    }
    if (r < 7) {
#pragma unroll
      for (int c = 0; c < 8; ++c) gvals[c] = gnext[c];
    }
  }
  // tail: remaining <128 ring entries
  while (qlen >= 64u) {
    __builtin_amdgcn_wave_barrier();
    uint32_t idx = hd + (uint32_t)lane;
    if (idx >= (uint32_t)QSEG) idx -= (uint32_t)QSEG;
    uint32_t p = q[idx];
    hd += 64u; if (hd >= (uint32_t)QSEG) hd -= (uint32_t)QSEG;
    qlen -= 64u;
    uint32_t v = score_bits(k0, k1, p) >> 9;
    if (v >= T) {
      uint32_t pos = atomicAdd(&lcnt, 1u);
      uint64_t key = (((uint64_t)((~v) & 0x7FFFFFu)) << 18) | p;
      if (pos < (uint32_t)LBUF) lbuf[pos] = key;
      else { uint32_t gp = atomicAdd(&cnt_bg[b], 1u);
             if (gp < (uint32_t)CAP2) list[(size_t)b * CAP2 + gp] = key; }
    }
  }
  if (qlen) {                        // final partial (<64 entries)
    __builtin_amdgcn_wave_barrier();
    if ((uint32_t)lane < qlen) {
      uint32_t idx = hd + (uint32_t)lane;
      if (idx >= (uint32_t)QSEG) idx -= (uint32_t)QSEG;
      uint32_t p = q[idx];
      uint32_t v = score_bits(k0, k1, p) >> 9;
      if (v >= T) {
        uint32_t pos = atomicAdd(&lcnt, 1u);
        uint64_t key = (((uint64_t)((~v) & 0x7FFFFFu)) << 18) | p;
        if (pos < (uint32_t)LBUF) lbuf[pos] = key;
        else { uint32_t gp = atomicAdd(&cnt_bg[b], 1u);
               if (gp < (uint32_t)CAP2) list[(size_t)b * CAP2 + gp] = key; }
      }
    }
  }
  // halo rows: roi bits only
  {
    int lowWords = (R0 - rlo) * 8;
    int nh = nwords - 1024;
    for (int i = wave; i < nh; i += 16) {
      int wi = i + ((i < lowWords) ? 0 : 1024);
      int absr = rlo + (wi >> 3);
      int c = wi & 7;
      uint32_t gv = (uint32_t)gb[absr * W + c * 64 + lane];
      uint64_t bw = __ballot((int)gv >= groi);
      if (lane == 0) sroi[wi] = bw;
    }
  }
  __syncthreads();
  // 11-wide row min over slab
  for (int wi = t; wi < nwords; wi += 1024) {
    int c = wi & 7;
    uint64_t cur = sroi[wi];
    uint64_t left  = (c > 0) ? sroi[wi - 1] : ~0ull;
    uint64_t right = (c < 7) ? sroi[wi + 1] : ~0ull;
    uint64_t res = cur;
#pragma unroll
    for (int s = 1; s <= 5; ++s) {
      res &= (cur >> s) | (right << (64 - s));
      res &= (cur << s) | (left >> (64 - s));
    }
    srow[wi] = res;
  }
  __syncthreads();
  // 11-tall col min for core rows (exactly 1024 words) + popcount
  {
    int coreRow = t >> 3, c = t & 7;
    int absr = R0 + coreRow;
    int s = absr - rlo;
    uint64_t res = srow[s * 8 + c];
#pragma unroll
    for (int d = 1; d <= 5; ++d) {
      if (absr - d >= 0) res &= srow[(s - d) * 8 + c];
      if (absr + d < H)  res &= srow[(s + d) * 8 + c];
    }
    erod[(size_t)b * WPI + absr * 8 + c] = res;
    uint32_t pc = (uint32_t)__popcll(res);
    for (int sh = 32; sh >= 1; sh >>= 1) pc += __shfl_down(pc, sh);
    if (lane == 0 && pc) atomicAdd(&Efg[b], pc);
  }
  __syncthreads();
  // bulk candidate append
  int m = min((int)lcnt, LBUF);
  if (t == 0) gbase = atomicAdd(&cnt_bg[b], (uint32_t)m);
  __syncthreads();
  uint32_t base = gbase;
  for (int i = t; i < m; i += 1024) {
    uint32_t pos = base + (uint32_t)i;
    if (pos < (uint32_t)CAP2) list[(size_t)b * CAP2 + pos] = lbuf[i];
  }
}

// ==== merged select+compose: TWO blocks per image (full-GPU compose). ====
__global__ __launch_bounds__(1024) void k_selcomp(const uint32_t* __restrict__ r1a,
                                                  const uint32_t* __restrict__ cnt_be,
                                                  const uint64_t* __restrict__ list_be,
                                                  const uint32_t* __restrict__ Tbg,
                                                  const uint32_t* __restrict__ keys,
                                                  const uint32_t* __restrict__ cnt_bg,
                                                  const uint64_t* __restrict__ list,
                                                  const uint32_t* __restrict__ Ea,
                                                  uint32_t* __restrict__ cnt_fg,
                                                  uint64_t* __restrict__ list_fg,
                                                  const uint64_t* __restrict__ bmE,
                                                  int* __restrict__ out) {
  __shared__ uint64_t Gbit[WPI];    // 32 KB bg bitmap
  __shared__ uint64_t Fbit[WPI];    // 32 KB fg bitmap (or bmE copy)
  __shared__ uint64_t pool[5248];   // 41 KB, carved per phase
  __shared__ uint32_t ecnt, tcnt, lcnt, gbase, sb2, sr2;
  int b = blockIdx.x >> 1, sub = blockIdx.x & 1, t = threadIdx.x;
  int bsub = b * 2 + sub;           // per-(image,sub) fg spill slot
  uint32_t* G32 = (uint32_t*)Gbit;
  uint32_t* F32 = (uint32_t*)Fbit;
  uint32_t* h = (uint32_t*)(pool + 2048);   // u32[4096]
  uint64_t* tie = pool + 4096;              // u64[1024]
  uint32_t* S = (uint32_t*)(pool + 5120);   // u32[256]
  uint32_t E = Ea[b];
  for (int i = t; i < WPI; i += 1024) Gbit[i] = 0;
  if (E > (uint32_t)NSEED)
    for (int i = t; i < WPI; i += 1024) Fbit[i] = 0;   // else copy overwrites
  if (t == 0) { ecnt = 0; tcnt = 0; }

  // ---------------- bg select (into Gbit) ----------------
  {
    uint64_t* ks = pool;            // u64[1024]
    uint64_t* ebuf = pool + 1024;   // u64[1024]
    int nbe = min((int)cnt_be[b], CAPS);
    if (t < nbe) ks[t] = list_be[(size_t)b * CAPS + t];
    __syncthreads();
    if (t < nbe) {
      uint64_t mk = ks[t];
      int rank = 0;
      for (int i = 0; i < nbe; ++i) rank += (ks[i] < mk) ? 1 : 0;
      int r = min((int)r1a[b], nbe);
      if (rank < r) {
        uint32_t p = (uint32_t)(mk & 0x3FFFFull);
        uint32_t v = score_bits(keys[b * 4 + 2], keys[b * 4 + 3], p) >> 9;
        if (v >= Tbg[b]) {
          uint32_t slot = atomicAdd(&ecnt, 1u);
          ebuf[slot] = (((uint64_t)((~v) & 0x7FFFFFu)) << 18) | p;
        }
      }
    }
    for (int i = t; i < 4096; i += 1024) h[i] = 0;
    __syncthreads();
    int n0 = min((int)cnt_bg[b], CAP2);
    int ne = (int)ecnt;
    int n = n0 + ne;
    if (n > 0) {
      uint32_t target = (uint32_t)min(NSEED, n);
      const uint64_t* lb = list + (size_t)b * CAP2;
      uint64_t K0 = (t < n0)        ? lb[t]        : 0;
      uint64_t K1 = (t + 1024 < n0) ? lb[t + 1024] : 0;
      uint64_t K2 = (t + 2048 < n0) ? lb[t + 2048] : 0;
      uint64_t K3 = (t + 3072 < n0) ? lb[t + 3072] : 0;
      uint64_t KE = (t < ne)        ? ebuf[t]      : 0;
      if (t < n0)        atomicAdd(&h[(uint32_t)(K0 >> 29)], 1u);
      if (t + 1024 < n0) atomicAdd(&h[(uint32_t)(K1 >> 29)], 1u);
      if (t + 2048 < n0) atomicAdd(&h[(uint32_t)(K2 >> 29)], 1u);
      if (t + 3072 < n0) atomicAdd(&h[(uint32_t)(K3 >> 29)], 1u);
      if (t < ne)        atomicAdd(&h[(uint32_t)(KE >> 29)], 1u);
      __syncthreads();
      if (t < 256) {
        uint32_t s = 0;
#pragma unroll
        for (int i = 0; i < 16; ++i) s += h[t * 16 + ((i + t) & 15)];   // rotated
        S[t] = s;
      }
      __syncthreads();
      for (int st = 1; st < 256; st <<= 1) {
        uint32_t v = 0;
        if (t < 256 && t >= st) v = S[t - st];
        __syncthreads();
        if (t < 256) S[t] += v;
        __syncthreads();
      }
      if (t < 256) {
        uint32_t before = (t == 0) ? 0u : S[t - 1];
        if (S[t] >= target && before < target) {
          uint32_t acc = before;
          for (int i = 0; i < 16; ++i) {
            uint32_t c = h[t * 16 + i];
            if (acc + c >= target) { sb2 = (uint32_t)(t * 16 + i); sr2 = target - acc; break; }
            acc += c;
          }
        }
      }
      __syncthreads();
      uint32_t b2 = sb2, r2 = sr2;
#define PROCB(KK, VALID) \
      if (VALID) { \
        uint32_t bin = (uint32_t)((KK) >> 29); \
        if (bin < b2) { \
          uint32_t p = (uint32_t)(KK) & 0x3FFFFu; \
          atomicOr(&G32[p >> 5], 1u << (p & 31)); \
        } else if (bin == b2) { \
          uint32_t pos = atomicAdd(&tcnt, 1u); \
          if (pos < 1024u) tie[pos] = (KK); \
        } \
      }
      PROCB(K0, t < n0) PROCB(K1, t + 1024 < n0) PROCB(K2, t + 2048 < n0)
      PROCB(K3, t + 3072 < n0) PROCB(KE, t < ne)
#undef PROCB
      __syncthreads();
      int m = min((int)tcnt, 1024);
      int r = min((int)r2, m);
      if (t < m) {
        uint64_t mk = tie[t];
        int rank = 0;
        for (int i = 0; i < m; ++i) rank += (tie[i] < mk) ? 1 : 0;
        if (rank < r) {
          uint32_t p = (uint32_t)mk & 0x3FFFFu;
          atomicOr(&G32[p >> 5], 1u << (p & 31));
        }
      }
    }
  }
  __syncthreads();   // Gbit complete; pool(ks/ebuf) dead

  // ---------------- fg select (into Fbit) ----------------
  {
    const uint64_t* eb = bmE + (size_t)b * WPI;
    if (E <= (uint32_t)NSEED) {
      for (int i = t; i < WPI; i += 1024) Fbit[i] = eb[i];   // all eligible
      __syncthreads();
    } else {
      uint64_t* lbuf = pool;   // u64[2048]
      if (t == 0) { lcnt = 0; tcnt = 0; }
      for (int i = t; i < 4096; i += 1024) h[i] = 0;
      __syncthreads();
      float tvf = floorf((1.0f - (float)MARGIN / (float)E) * 8388608.0f);
      uint32_t T = (uint32_t)fmaxf(tvf, 0.0f);
      uint32_t k0 = keys[b * 4 + 0], k1 = keys[b * 4 + 1];
      int lane = t & 63;
      for (int k = 0; k < HW / 1024; ++k) {
        uint32_t p = (uint32_t)(k * 1024 + t);
        uint64_t wbits = eb[p >> 6];
        if ((wbits >> lane) & 1ull) {
          uint32_t v = score_bits(k0, k1, p) >> 9;
          if (v >= T) {
            uint32_t pos = atomicAdd(&lcnt, 1u);
            uint64_t key = (((uint64_t)((~v) & 0x7FFFFFu)) << 18) | p;
            if (pos < (uint32_t)LBUF) lbuf[pos] = key;
            else { uint32_t gp = atomicAdd(&cnt_fg[bsub], 1u);
                   if (gp < (uint32_t)CAP2) list_fg[(size_t)bsub * CAP2 + gp] = key; }
          }
        }
      }
      __syncthreads();
      int m2 = min((int)lcnt, LBUF);
      if (t == 0) gbase = atomicAdd(&cnt_fg[bsub], (uint32_t)m2);
      __syncthreads();
      for (int i = t; i < m2; i += 1024) {
        uint32_t pos = gbase + (uint32_t)i;
        if (pos < (uint32_t)CAP2) list_fg[(size_t)bsub * CAP2 + pos] = lbuf[i];
      }
      __syncthreads();
      int n = min((int)cnt_fg[bsub], CAP2);
      if (n > 0) {
        uint32_t target = (uint32_t)min(NSEED, n);
        const uint64_t* lb = list_fg + (size_t)bsub * CAP2;
        uint64_t K0 = (t < n)        ? lb[t]        : 0;
        uint64_t K1 = (t + 1024 < n) ? lb[t + 1024] : 0;
        uint64_t K2 = (t + 2048 < n) ? lb[t + 2048] : 0;
        uint64_t K3 = (t + 3072 < n) ? lb[t + 3072] : 0;
        if (t < n)        atomicAdd(&h[(uint32_t)(K0 >> 29)], 1u);
        if (t + 1024 < n) atomicAdd(&h[(uint32_t)(K1 >> 29)], 1u);
        if (t + 2048 < n) atomicAdd(&h[(uint32_t)(K2 >> 29)], 1u);
        if (t + 3072 < n) atomicAdd(&h[(uint32_t)(K3 >> 29)], 1u);
        __syncthreads();
        if (t < 256) {
          uint32_t s = 0;
#pragma unroll
          for (int i = 0; i < 16; ++i) s += h[t * 16 + ((i + t) & 15)];   // rotated
          S[t] = s;
        }
        __syncthreads();
        for (int st = 1; st < 256; st <<= 1) {
          uint32_t v = 0;
          if (t < 256 && t >= st) v = S[t - st];
          __syncthreads();
          if (t < 256) S[t] += v;
          __syncthreads();
        }
        if (t < 256) {
          uint32_t before = (t == 0) ? 0u : S[t - 1];
          if (S[t] >= target && before < target) {
            uint32_t acc = before;
            for (int i = 0; i < 16; ++i) {
              uint32_t c = h[t * 16 + i];
              if (acc + c >= target) { sb2 = (uint32_t)(t * 16 + i); sr2 = target - acc; break; }
              acc += c;
            }
          }
        }
        __syncthreads();
        uint32_t b2 = sb2, r2 = sr2;
#define PROCF(KK, VALID) \
        if (VALID) { \
          uint32_t bin = (uint32_t)((KK) >> 29); \
          if (bin < b2) { \
            uint32_t p = (uint32_t)(KK) & 0x3FFFFu; \
            atomicOr(&F32[p >> 5], 1u << (p & 31)); \
          } else if (bin == b2) { \
            uint32_t pos = atomicAdd(&tcnt, 1u); \
            if (pos < 1024u) tie[pos] = (KK); \
          } \
        }
        PROCF(K0, t < n) PROCF(K1, t + 1024 < n) PROCF(K2, t + 2048 < n)
        PROCF(K3, t + 3072 < n)
#undef PROCF
        __syncthreads();
        int m = min((int)tcnt, 1024);
        int r = min((int)r2, m);
        if (t < m) {
          uint64_t mk = tie[t];
          int rank = 0;
          for (int i = 0; i < m; ++i) rank += (tie[i] < mk) ? 1 : 0;
          if (rank < r) {
            uint32_t p = (uint32_t)mk & 0x3FFFFu;
            atomicOr(&F32[p >> 5], 1u << (p & 31));
          }
        }
      }
      __syncthreads();
    }
  }
  __syncthreads();   // Fbit complete; pool fully dead

  // ------- compose this block's half: 4 iters x {1024 words, 8192 int4} -----
  uint64_t* FdS = pool;          // u64[512]
  uint64_t* BdS = pool + 512;    // u64[512]
  for (int it = 0; it < 4; ++it) {
    {
      int s = t >> 7, xx = t & 127;
      int w = xx & 63;
      int rg = sub * 32 + it * 8 + s;
      int r = rg * 8 + (w >> 3), c = w & 7;
      const uint64_t* src = (xx < 64) ? Fbit : Gbit;
      uint64_t d = 0;
#pragma unroll
      for (int dr = -1; dr <= 1; ++dr) {
        int rr = r + dr;
        if (rr < 0 || rr >= H) continue;
        int wi = rr * 8 + c;
        uint64_t cur = src[wi];
        uint64_t lf = (c > 0) ? src[wi - 1] : 0ull;
        uint64_t rt = (c < 7) ? src[wi + 1] : 0ull;
        d |= cur | (cur << 1) | (lf >> 63) | (cur >> 1) | (rt << 63);
      }
      if (xx < 64) FdS[s * 64 + w] = d; else BdS[s * 64 + w] = d;
    }
    __syncthreads();
    int4* ob = (int4*)out + (size_t)b * (HW / 4) + (size_t)sub * (HW / 8)
             + (size_t)it * 8192;
#pragma unroll
    for (int k2 = 0; k2 < 8; ++k2) {
      int idx = k2 * 1024 + t;         // [0, 8192)
      int ss = idx >> 10, i = idx & 1023;
      int ww = i >> 4, sub4 = i & 15;
      uint64_t Fd = FdS[ss * 64 + ww], Bd = BdS[ss * 64 + ww];
      uint64_t ov = Fd & Bd;
      Fd &= ~ov; Bd &= ~ov;
      int sh = sub4 * 4;
      int4 o;
      o.x = ((Fd >> (sh + 0)) & 1ull) ? 1 : (((Bd >> (sh + 0)) & 1ull) ? 0 : -255);
      o.y = ((Fd >> (sh + 1)) & 1ull) ? 1 : (((Bd >> (sh + 1)) & 1ull) ? 0 : -255);
      o.z = ((Fd >> (sh + 2)) & 1ull) ? 1 : (((Bd >> (sh + 2)) & 1ull) ? 0 : -255);
      o.w = ((Fd >> (sh + 3)) & 1ull) ? 1 : (((Bd >> (sh + 3)) & 1ull) ? 0 : -255);
      ob[idx] = o;
    }
    __syncthreads();
  }
}

extern "C" void kernel_launch(void* const* d_in, const int* in_sizes, int n_in,
                              void* d_out, int out_size, void* d_ws, size_t ws_size,
                              hipStream_t stream) {
  (void)in_sizes; (void)n_in; (void)out_size; (void)ws_size;
  const float* x = (const float*)d_in[0];
  int* out = (int*)d_out;
  char* ws = (char*)d_ws;

  // g (u16 bins, 64 MB) lives in the OUTPUT buffer (128 MB): written by
  // k_binify, read only by k_main, fully overwritten by k_selcomp at the end.
  u16* g = (u16*)d_out;

  // ---- workspace layout ----
  uint32_t* keys   = (uint32_t*)(ws + 0);       // 2048
  uint32_t* kbg    = (uint32_t*)(ws + 2048);    // 512
  int*      th     = (int*)     (ws + 2560);    // 512
  uint32_t* b1a    = (uint32_t*)(ws + 3072);    // 512
  uint32_t* r1a    = (uint32_t*)(ws + 3584);
  uint32_t* Tbg    = (uint32_t*)(ws + 4096);
  // ---- zeroed by the tiny memset below ----
  uint32_t* Efg    = (uint32_t*)(ws + 4608);    // 512
  uint32_t* cnt_be = (uint32_t*)(ws + 5120);    // 512
  uint32_t* cnt_bg = (uint32_t*)(ws + 5632);    // 512
  uint32_t* cnt_fg = (uint32_t*)(ws + 6144);    // 1024 (256 slots)
  uint32_t* done   = (uint32_t*)(ws + 7168);    // 512
  uint32_t* gh      = (uint32_t*)(ws + 8192);                      // 8 MB
  uint64_t* list    = (uint64_t*)(ws + 8192 + 8388608);            // 4 MB (bg)
  uint64_t* list_be = (uint64_t*)(ws + 8192 + 8388608 + 4194304);  // 1 MB
  uint64_t* bmE     = (uint64_t*)(ws + 8192 + 8388608 + 5242880);  // 4 MB
  uint64_t* list_fg = (uint64_t*)gh;   // gh dead after binify-otsu; 256*CAP2*8B

  hipMemsetAsync(ws + 4608, 0, 3072, stream);   // counters + done flags
  k_binify  <<<BATCH * 4, 1024, 0, stream>>>((const float4*)x, g, gh, keys, kbg,
                                             Tbg, done, th, b1a, r1a);
  k_main    <<<BATCH * 4, 1024, 0, stream>>>(g, x, th, b1a, Tbg, keys,
                                             Efg, cnt_bg, list, cnt_be, list_be, bmE);
  k_selcomp <<<BATCH * 2, 1024, 0, stream>>>(r1a, cnt_be, list_be, Tbg, keys,
                                             cnt_bg, list, Efg, cnt_fg, list_fg,
                                             bmE, out);
}

// Round 12
// 334.609 us; speedup vs baseline: 1.7970x; 1.7970x over previous
//
#include <hip/hip_runtime.h>
#include <cstdint>

typedef unsigned short u16;

constexpr int BATCH = 128;
constexpr int H = 512, W = 512;
constexpr int HW = H * W;       // 2^18
constexpr int WPR = W / 64;     // 8 words per row
constexpr int WPI = HW / 64;    // 4096 words per image
constexpr int NSEED = 1000;
constexpr int MARGIN = 3000;    // expected candidate count for threshold select
constexpr int CAP2 = 4096;      // per-image candidate list capacity
constexpr int CAPS = 1024;      // tie list capacity (mean ~64)
constexpr int LBUF = 2048;      // per-block LDS candidate buffer
constexpr int NBIN = 4096;      // gh stride; bins 0..4079 used (g = floor(v*4080))
constexpr int QSEG = 256;       // per-wave ring: drain-128 -> carry<128 + append<=64

// ---------------- Threefry-2x32 (20 rounds), bit-exact vs JAX ----------------
__device__ __forceinline__ uint32_t rotl32(uint32_t v, int d) {
  return (v << d) | (v >> (32 - d));
}

__device__ __forceinline__ void tf2x32(uint32_t k0, uint32_t k1,
                                       uint32_t x0, uint32_t x1,
                                       uint32_t &o0, uint32_t &o1) {
  uint32_t ks2 = k0 ^ k1 ^ 0x1BD11BDAu;
  x0 += k0; x1 += k1;
  x0 += x1; x1 = rotl32(x1, 13); x1 ^= x0;
  x0 += x1; x1 = rotl32(x1, 15); x1 ^= x0;
  x0 += x1; x1 = rotl32(x1, 26); x1 ^= x0;
  x0 += x1; x1 = rotl32(x1, 6);  x1 ^= x0;
  x0 += k1; x1 += ks2 + 1u;
  x0 += x1; x1 = rotl32(x1, 17); x1 ^= x0;
  x0 += x1; x1 = rotl32(x1, 29); x1 ^= x0;
  x0 += x1; x1 = rotl32(x1, 16); x1 ^= x0;
  x0 += x1; x1 = rotl32(x1, 24); x1 ^= x0;
  x0 += ks2; x1 += k0 + 2u;
  x0 += x1; x1 = rotl32(x1, 13); x1 ^= x0;
  x0 += x1; x1 = rotl32(x1, 15); x1 ^= x0;
  x0 += x1; x1 = rotl32(x1, 26); x1 ^= x0;
  x0 += x1; x1 = rotl32(x1, 6);  x1 ^= x0;
  x0 += k0; x1 += k1 + 3u;
  x0 += x1; x1 = rotl32(x1, 17); x1 ^= x0;
  x0 += x1; x1 = rotl32(x1, 29); x1 ^= x0;
  x0 += x1; x1 = rotl32(x1, 16); x1 ^= x0;
  x0 += x1; x1 = rotl32(x1, 24); x1 ^= x0;
  x0 += k1; x1 += ks2 + 4u;
  x0 += x1; x1 = rotl32(x1, 13); x1 ^= x0;
  x0 += x1; x1 = rotl32(x1, 15); x1 ^= x0;
  x0 += x1; x1 = rotl32(x1, 26); x1 ^= x0;
  x0 += x1; x1 = rotl32(x1, 6);  x1 ^= x0;
  x0 += ks2; x1 += k0 + 5u;
  o0 = x0; o1 = x1;
}

__device__ __forceinline__ uint32_t score_bits(uint32_t k0, uint32_t k1, uint32_t i) {
  uint32_t a, c; tf2x32(k0, k1, 0u, i, a, c);
  return a ^ c;
}

// ---------------- per-image keys + nbr_bg + bg score threshold ----------------
__device__ __forceinline__ void keygen(int b, uint32_t* keys, uint32_t* kbg,
                                       uint32_t* Tbg) {
  uint32_t kb0, kb1; tf2x32(0u, 42u, 0u, (uint32_t)b, kb0, kb1);
  uint32_t kf0, kf1; tf2x32(kb0, kb1, 0u, 0u, kf0, kf1);
  uint32_t kB0, kB1; tf2x32(kb0, kb1, 0u, 1u, kB0, kB1);
  uint32_t kz0, kz1; tf2x32(kb0, kb1, 0u, 2u, kz0, kz1);
  uint32_t za, zc; tf2x32(kz0, kz1, 0u, 0u, za, zc);
  uint32_t zb = za ^ zc;
  keys[b * 4 + 0] = kf0; keys[b * 4 + 1] = kf1;
  keys[b * 4 + 2] = kB0; keys[b * 4 + 3] = kB1;
  float uu = __uint_as_float((zb >> 9) | 0x3f800000u) - 1.0f;
  float span = __fsub_rn(0.7f, 0.3f);
  float z = __fadd_rn(__fmul_rn(uu, span), 0.3f);
  z = fmaxf(0.3f, z);
  float nb = ceilf(__fmul_rn(z, (float)HW));
  uint32_t K = (uint32_t)nb;
  kbg[b] = K;
  float tv = floorf((1.0f - (float)MARGIN / (float)K) * 8388608.0f);
  Tbg[b] = (uint32_t)fmaxf(tv, 0.0f);
}

// -------- fused x sweep: per-sub 4080-bin hist (pure stores) + u16 bins +
//          keygen + counter zeroing (replaces host memset) --------
__global__ __launch_bounds__(1024) void k_binify(const float4* __restrict__ x4,
                                                 u16* __restrict__ g,
                                                 uint32_t* __restrict__ gh,
                                                 uint32_t* __restrict__ keys,
                                                 uint32_t* __restrict__ kbg,
                                                 uint32_t* __restrict__ Tbg,
                                                 uint32_t* __restrict__ Efg,
                                                 uint32_t* __restrict__ cnt_fg,
                                                 uint32_t* __restrict__ cnt_be,
                                                 uint32_t* __restrict__ cnt_bg) {
  __shared__ uint32_t h[NBIN];
  int b = blockIdx.x >> 2, sub = blockIdx.x & 3, t = threadIdx.x;
  if (blockIdx.x == 0 && t < BATCH) {
    keygen(t, keys, kbg, Tbg);
    Efg[t] = 0; cnt_be[t] = 0; cnt_bg[t] = 0;
  }
  if (blockIdx.x == 0 && t < 2 * BATCH) cnt_fg[t] = 0;   // per-(image,sub) slots
  for (int i = t; i < NBIN; i += 1024) h[i] = 0;
  __syncthreads();
  const float4* xb = x4 + ((size_t)b * HW + (size_t)sub * (HW / 4)) / 4;
  ushort4* gb4 = (ushort4*)g + ((size_t)b * HW + (size_t)sub * (HW / 4)) / 4;
  for (int i = t; i < HW / 16; i += 1024) {
    float4 v4 = xb[i];
    int g0 = (int)floorf(__fmul_rn(v4.x, 4080.0f)); g0 = min(max(g0, 0), 4079);
    int g1 = (int)floorf(__fmul_rn(v4.y, 4080.0f)); g1 = min(max(g1, 0), 4079);
    int g2 = (int)floorf(__fmul_rn(v4.z, 4080.0f)); g2 = min(max(g2, 0), 4079);
    int g3 = (int)floorf(__fmul_rn(v4.w, 4080.0f)); g3 = min(max(g3, 0), 4079);
    atomicAdd(&h[g0], 1u);
    atomicAdd(&h[g1], 1u);
    atomicAdd(&h[g2], 1u);
    atomicAdd(&h[g3], 1u);
    ushort4 o;
    o.x = (u16)g0; o.y = (u16)g1; o.z = (u16)g2; o.w = (u16)g3;
    gb4[i] = o;
  }
  __syncthreads();
  uint32_t* dst = gh + ((size_t)blockIdx.x << 12);   // per-(b,sub) histogram
  for (int i = t; i < NBIN; i += 1024) dst[i] = h[i];
}

// ---- paired Otsu cumsum: count+mass trees in ONE 17-barrier pass. ----
__device__ __forceinline__ void lds_tree_cumsum256x2(float* Lc, float* Sc,
                                                     float* Lm, float* Sm, int tid) {
  const int off[9] = {0, 256, 384, 448, 480, 496, 504, 508, 510};
  const int sz[9]  = {256, 128, 64, 32, 16, 8, 4, 2, 1};
  for (int l = 0; l < 8; ++l) {
    int o = off[l], on = off[l + 1], n = sz[l + 1];
    if (tid < n) {
      Lc[on + tid] = __fadd_rn(Lc[o + 2 * tid], Lc[o + 2 * tid + 1]);
      Lm[on + tid] = __fadd_rn(Lm[o + 2 * tid], Lm[o + 2 * tid + 1]);
    }
    __syncthreads();
  }
  if (tid == 0) { Sc[off[8]] = Lc[off[8]]; Sm[off[8]] = Lm[off[8]]; }
  __syncthreads();
  for (int l = 7; l >= 0; --l) {
    int o = off[l], on = off[l + 1], hn = sz[l] / 2;
    if (tid == 0) { Sc[o] = Lc[o]; Sm[o] = Lm[o]; }
    if (tid < hn) { Sc[o + 2 * tid + 1] = Sc[on + tid]; Sm[o + 2 * tid + 1] = Sm[on + tid]; }
    if (tid >= 1 && tid < hn) {
      Sc[o + 2 * tid] = __fadd_rn(Sc[on + tid - 1], Lc[o + 2 * tid]);
      Sm[o + 2 * tid] = __fadd_rn(Sm[on + tid - 1], Lm[o + 2 * tid]);
    }
    __syncthreads();
  }
}

// ---- dedicated Otsu + K-scan: one block (256 thr, 4 waves) per image. ----
__global__ __launch_bounds__(256) void k_otsu(const uint32_t* __restrict__ gh,
                                              const uint32_t* __restrict__ kbg,
                                              int* __restrict__ th_out,
                                              uint32_t* __restrict__ b1a,
                                              uint32_t* __restrict__ r1a) {
  __shared__ uint32_t h[NBIN];
  __shared__ float Lc[511], Sc[511], Lm[511], Sm[511];
  __shared__ float av[4];
  __shared__ int ai[4];
  int b = blockIdx.x, t = threadIdx.x;
  const uint32_t* g0 = gh + ((size_t)(b * 4 + 0) << 12);
  const uint32_t* g1 = gh + ((size_t)(b * 4 + 1) << 12);
  const uint32_t* g2 = gh + ((size_t)(b * 4 + 2) << 12);
  const uint32_t* g3 = gh + ((size_t)(b * 4 + 3) << 12);
  for (int i = t; i < NBIN; i += 256) h[i] = g0[i] + g1[i] + g2[i] + g3[i];
  __syncthreads();
  uint32_t hv = 0;
#pragma unroll
  for (int i = 0; i < 16; ++i) hv += h[t * 16 + ((i + t) & 15)];   // rotated
  Lc[t] = (float)hv;
  Lm[t] = __fmul_rn((float)hv, (float)t);
  __syncthreads();
  lds_tree_cumsum256x2(Lc, Sc, Lm, Sm, t);   // 17 barriers @ 4 waves
  uint32_t K = kbg[b];
  {
    float total = (float)HW;
    float mT = Sm[255];
    float w = Sc[t];
    float denom = __fmul_rn(w, __fsub_rn(total, w));
    float s = 0.0f;
    if (denom > 0.0f) {
      float d  = __fsub_rn(__fmul_rn(mT, w), __fmul_rn(total, Sm[t]));
      float nu = __fmul_rn(d, d);
      float dd = __fmul_rn(__fmul_rn(denom, total), total);
      s = __fdiv_rn(nu, dd);
    }
    float bv = s; int bidx = t;
#pragma unroll
    for (int d = 32; d >= 1; d >>= 1) {
      float ov = __shfl_xor(bv, d, 64);
      int oi = __shfl_xor(bidx, d, 64);
      if (ov > bv || (ov == bv && oi < bidx)) { bv = ov; bidx = oi; }
    }
    if ((t & 63) == 0) { av[t >> 6] = bv; ai[t >> 6] = bidx; }
    bool gf = (Sc[t] >= (float)K) && (t == 0 || Sc[t - 1] < (float)K);
    if (gf) {   // exactly one thread; 16-bin inner scan
      uint32_t accv = (t == 0) ? 0u : (uint32_t)Sc[t - 1];
      uint32_t b1v = 0, r1v = 1;
      for (int bin = t * 16; bin < t * 16 + 16; ++bin) {
        uint32_t cc = h[bin];
        if (accv + cc >= K) { b1v = (uint32_t)bin; r1v = K - accv; break; }
        accv += cc;
      }
      b1a[b] = b1v; r1a[b] = r1v;
    }
  }
  __syncthreads();
  if (t == 0) {
    float bv = av[0]; int bidx = ai[0];
#pragma unroll
    for (int wv = 1; wv < 4; ++wv) {
      float ov = av[wv]; int oi = ai[wv];
      if (ov > bv || (ov == bv && oi < bidx)) { bv = ov; bidx = oi; }
    }
    int bi = bidx;
    if (bi == 0) bi = 1;
    if (bi == 255) bi = 254;
    th_out[b] = bi;
  }
}

// ==== mega-fused lean body: ROI bits + 11x11 erosion + E count + bg
//      candidates. Drain-128 + next-row register prefetch. ====
__global__ __launch_bounds__(1024) void k_main(const u16* __restrict__ gq,
                                               const float* __restrict__ x,
                                               const int* __restrict__ th,
                                               const uint32_t* __restrict__ b1a,
                                               const uint32_t* __restrict__ Tbg,
                                               const uint32_t* __restrict__ keys,
                                               uint32_t* __restrict__ Efg,
                                               uint32_t* __restrict__ cnt_bg,
                                               uint64_t* __restrict__ list,
                                               uint32_t* __restrict__ cnt_be,
                                               uint64_t* __restrict__ list_be,
                                               uint64_t* __restrict__ erod) {
  __shared__ uint64_t sroi[1104];      // roi bits, slab rows (<=138) x 8 words
  __shared__ uint64_t srow[1104];      // after 11-wide row min
  __shared__ uint64_t lbuf[LBUF];      // candidate keys
  __shared__ uint32_t wq[16 * QSEG];   // per-wave eligible rings (16 KB)
  __shared__ uint32_t lcnt, gbase;
  int b = blockIdx.x >> 2, sub = blockIdx.x & 3, t = threadIdx.x;
  int wave = t >> 6, lane = t & 63;
  int R0 = sub * 128;
  int rlo = max(R0 - 5, 0), rhi = min(R0 + 133, H);
  int nwords = (rhi - rlo) * 8;
  const u16* gb = gq + (size_t)b * HW;
  const float* xb = x + (size_t)b * HW;
  int groi = (th[b] + 1) << 4;     // g >= 16*(th+1)  <=>  floor(v*255) > th
  uint32_t b1 = b1a[b];
  uint32_t T = Tbg[b];
  uint32_t k0 = keys[b * 4 + 2], k1 = keys[b * 4 + 3];
  if (t == 0) lcnt = 0;
  __syncthreads();
  uint32_t* q = wq + wave * QSEG;
  uint32_t qlen = 0, hd = 0;
  uint64_t lmask = (1ull << lane) - 1ull;
  // phase A: wave owns 8 core rows; prefetch next row; drain-128 per column
  int absr0 = R0 + wave * 8;
  u16 gvals[8];
  {
    const u16* gp8 = gb + absr0 * W + lane;
#pragma unroll
    for (int c = 0; c < 8; ++c) gvals[c] = gp8[c * 64];
  }
  for (int r = 0; r < 8; ++r) {
    int absr = absr0 + r;
    int rowbase = absr * W + lane;
    int swbase = (absr - rlo) * 8;
    u16 gnext[8];
    if (r < 7) {
      const u16* gp8 = gb + (absr + 1) * W + lane;
#pragma unroll
      for (int c = 0; c < 8; ++c) gnext[c] = gp8[c * 64];
    }
#pragma unroll
    for (int c = 0; c < 8; ++c) {
      uint32_t gv = (uint32_t)gvals[c];
      uint64_t bw = __ballot((int)gv >= groi);
      if (lane == 0) sroi[swbase + c] = bw;
      bool elig = gv < b1;
      uint64_t m = __ballot(elig);
      if (elig) {
        uint32_t rank = (uint32_t)__popcll(m & lmask);
        uint32_t idx = hd + qlen + rank;
        if (idx >= (uint32_t)QSEG) idx -= (uint32_t)QSEG;
        q[idx] = (uint32_t)(rowbase + c * 64);
      }
      qlen += (uint32_t)__popcll(m);
      if (gv == b1) {   // rare (~64/image): boundary bin, exact-value tie
        uint32_t gp = atomicAdd(&cnt_be[b], 1u);
        if (gp < (uint32_t)CAPS)
          list_be[(size_t)b * CAPS + gp] =
              (((uint64_t)__float_as_uint(xb[rowbase + c * 64])) << 18) |
              (uint32_t)(rowbase + c * 64);
      }
      while (qlen >= 128u) {         // wave-uniform; 2 indep threefrys/lane
        __builtin_amdgcn_wave_barrier();
        uint32_t i0 = hd + (uint32_t)lane;
        if (i0 >= (uint32_t)QSEG) i0 -= (uint32_t)QSEG;
        uint32_t i1 = hd + 64u + (uint32_t)lane;
        if (i1 >= (uint32_t)QSEG) i1 -= (uint32_t)QSEG;
        uint32_t p0 = q[i0];
        uint32_t p1 = q[i1];
        hd += 128u; if (hd >= (uint32_t)QSEG) hd -= (uint32_t)QSEG;
        qlen -= 128u;
        uint32_t v0 = score_bits(k0, k1, p0) >> 9;
        uint32_t v1 = score_bits(k0, k1, p1) >> 9;
        if (v0 >= T) {
          uint32_t pos = atomicAdd(&lcnt, 1u);
          uint64_t key = (((uint64_t)((~v0) & 0x7FFFFFu)) << 18) | p0;
          if (pos < (uint32_t)LBUF) lbuf[pos] = key;
          else { uint32_t gp = atomicAdd(&cnt_bg[b], 1u);
                 if (gp < (uint32_t)CAP2) list[(size_t)b * CAP2 + gp] = key; }
        }
        if (v1 >= T) {
          uint32_t pos = atomicAdd(&lcnt, 1u);
          uint64_t key = (((uint64_t)((~v1) & 0x7FFFFFu)) << 18) | p1;
          if (pos < (uint32_t)LBUF) lbuf[pos] = key;
          else { uint32_t gp = atomicAdd(&cnt_bg[b], 1u);
                 if (gp < (uint32_t)CAP2) list[(size_t)b * CAP2 + gp] = key; }
        }
      }
    }
    if (r < 7) {
#pragma unroll
      for (int c = 0; c < 8; ++c) gvals[c] = gnext[c];
    }
  }
  // tail: remaining <128 ring entries
  while (qlen >= 64u) {
    __builtin_amdgcn_wave_barrier();
    uint32_t idx = hd + (uint32_t)lane;
    if (idx >= (uint32_t)QSEG) idx -= (uint32_t)QSEG;
    uint32_t p = q[idx];
    hd += 64u; if (hd >= (uint32_t)QSEG) hd -= (uint32_t)QSEG;
    qlen -= 64u;
    uint32_t v = score_bits(k0, k1, p) >> 9;
    if (v >= T) {
      uint32_t pos = atomicAdd(&lcnt, 1u);
      uint64_t key = (((uint64_t)((~v) & 0x7FFFFFu)) << 18) | p;
      if (pos < (uint32_t)LBUF) lbuf[pos] = key;
      else { uint32_t gp = atomicAdd(&cnt_bg[b], 1u);
             if (gp < (uint32_t)CAP2) list[(size_t)b * CAP2 + gp] = key; }
    }
  }
  if (qlen) {                        // final partial (<64 entries)
    __builtin_amdgcn_wave_barrier();
    if ((uint32_t)lane < qlen) {
      uint32_t idx = hd + (uint32_t)lane;
      if (idx >= (uint32_t)QSEG) idx -= (uint32_t)QSEG;
      uint32_t p = q[idx];
      uint32_t v = score_bits(k0, k1, p) >> 9;
      if (v >= T) {
        uint32_t pos = atomicAdd(&lcnt, 1u);
        uint64_t key = (((uint64_t)((~v) & 0x7FFFFFu)) << 18) | p;
        if (pos < (uint32_t)LBUF) lbuf[pos] = key;
        else { uint32_t gp = atomicAdd(&cnt_bg[b], 1u);
               if (gp < (uint32_t)CAP2) list[(size_t)b * CAP2 + gp] = key; }
      }
    }
  }
  // halo rows: roi bits only
  {
    int lowWords = (R0 - rlo) * 8;
    int nh = nwords - 1024;
    for (int i = wave; i < nh; i += 16) {
      int wi = i + ((i < lowWords) ? 0 : 1024);
      int absr = rlo + (wi >> 3);
      int c = wi & 7;
      uint32_t gv = (uint32_t)gb[absr * W + c * 64 + lane];
      uint64_t bw = __ballot((int)gv >= groi);
      if (lane == 0) sroi[wi] = bw;
    }
  }
  __syncthreads();
  // 11-wide row min over slab
  for (int wi = t; wi < nwords; wi += 1024) {
    int c = wi & 7;
    uint64_t cur = sroi[wi];
    uint64_t left  = (c > 0) ? sroi[wi - 1] : ~0ull;
    uint64_t right = (c < 7) ? sroi[wi + 1] : ~0ull;
    uint64_t res = cur;
#pragma unroll
    for (int s = 1; s <= 5; ++s) {
      res &= (cur >> s) | (right << (64 - s));
      res &= (cur << s) | (left >> (64 - s));
    }
    srow[wi] = res;
  }
  __syncthreads();
  // 11-tall col min for core rows (exactly 1024 words) + popcount
  {
    int coreRow = t >> 3, c = t & 7;
    int absr = R0 + coreRow;
    int s = absr - rlo;
    uint64_t res = srow[s * 8 + c];
#pragma unroll
    for (int d = 1; d <= 5; ++d) {
      if (absr - d >= 0) res &= srow[(s - d) * 8 + c];
      if (absr + d < H)  res &= srow[(s + d) * 8 + c];
    }
    erod[(size_t)b * WPI + absr * 8 + c] = res;
    uint32_t pc = (uint32_t)__popcll(res);
    for (int sh = 32; sh >= 1; sh >>= 1) pc += __shfl_down(pc, sh);
    if (lane == 0 && pc) atomicAdd(&Efg[b], pc);
  }
  __syncthreads();
  // bulk candidate append
  int m = min((int)lcnt, LBUF);
  if (t == 0) gbase = atomicAdd(&cnt_bg[b], (uint32_t)m);
  __syncthreads();
  uint32_t base = gbase;
  for (int i = t; i < m; i += 1024) {
    uint32_t pos = base + (uint32_t)i;
    if (pos < (uint32_t)CAP2) list[(size_t)b * CAP2 + pos] = lbuf[i];
  }
}

// ==== merged select+compose: TWO blocks per image (full-GPU compose). ====
__global__ __launch_bounds__(1024) void k_selcomp(const uint32_t* __restrict__ r1a,
                                                  const uint32_t* __restrict__ cnt_be,
                                                  const uint64_t* __restrict__ list_be,
                                                  const uint32_t* __restrict__ Tbg,
                                                  const uint32_t* __restrict__ keys,
                                                  const uint32_t* __restrict__ cnt_bg,
                                                  const uint64_t* __restrict__ list,
                                                  const uint32_t* __restrict__ Ea,
                                                  uint32_t* __restrict__ cnt_fg,
                                                  uint64_t* __restrict__ list_fg,
                                                  const uint64_t* __restrict__ bmE,
                                                  int* __restrict__ out) {
  __shared__ uint64_t Gbit[WPI];    // 32 KB bg bitmap
  __shared__ uint64_t Fbit[WPI];    // 32 KB fg bitmap (or bmE copy)
  __shared__ uint64_t pool[5248];   // 41 KB, carved per phase
  __shared__ uint32_t ecnt, tcnt, lcnt, gbase, sb2, sr2;
  int b = blockIdx.x >> 1, sub = blockIdx.x & 1, t = threadIdx.x;
  int bsub = b * 2 + sub;           // per-(image,sub) fg spill slot
  uint32_t* G32 = (uint32_t*)Gbit;
  uint32_t* F32 = (uint32_t*)Fbit;
  uint32_t* h = (uint32_t*)(pool + 2048);   // u32[4096]
  uint64_t* tie = pool + 4096;              // u64[1024]
  uint32_t* S = (uint32_t*)(pool + 5120);   // u32[256]
  uint32_t E = Ea[b];
  for (int i = t; i < WPI; i += 1024) Gbit[i] = 0;
  if (E > (uint32_t)NSEED)
    for (int i = t; i < WPI; i += 1024) Fbit[i] = 0;   // else copy overwrites
  if (t == 0) { ecnt = 0; tcnt = 0; }

  // ---------------- bg select (into Gbit) ----------------
  {
    uint64_t* ks = pool;            // u64[1024]
    uint64_t* ebuf = pool + 1024;   // u64[1024]
    int nbe = min((int)cnt_be[b], CAPS);
    if (t < nbe) ks[t] = list_be[(size_t)b * CAPS + t];
    __syncthreads();
    if (t < nbe) {
      uint64_t mk = ks[t];
      int rank = 0;
      for (int i = 0; i < nbe; ++i) rank += (ks[i] < mk) ? 1 : 0;
      int r = min((int)r1a[b], nbe);
      if (rank < r) {
        uint32_t p = (uint32_t)(mk & 0x3FFFFull);
        uint32_t v = score_bits(keys[b * 4 + 2], keys[b * 4 + 3], p) >> 9;
        if (v >= Tbg[b]) {
          uint32_t slot = atomicAdd(&ecnt, 1u);
          ebuf[slot] = (((uint64_t)((~v) & 0x7FFFFFu)) << 18) | p;
        }
      }
    }
    for (int i = t; i < 4096; i += 1024) h[i] = 0;
    __syncthreads();
    int n0 = min((int)cnt_bg[b], CAP2);
    int ne = (int)ecnt;
    int n = n0 + ne;
    if (n > 0) {
      uint32_t target = (uint32_t)min(NSEED, n);
      const uint64_t* lb = list + (size_t)b * CAP2;
      uint64_t K0 = (t < n0)        ? lb[t]        : 0;
      uint64_t K1 = (t + 1024 < n0) ? lb[t + 1024] : 0;
      uint64_t K2 = (t + 2048 < n0) ? lb[t + 2048] : 0;
      uint64_t K3 = (t + 3072 < n0) ? lb[t + 3072] : 0;
      uint64_t KE = (t < ne)        ? ebuf[t]      : 0;
      if (t < n0)        atomicAdd(&h[(uint32_t)(K0 >> 29)], 1u);
      if (t + 1024 < n0) atomicAdd(&h[(uint32_t)(K1 >> 29)], 1u);
      if (t + 2048 < n0) atomicAdd(&h[(uint32_t)(K2 >> 29)], 1u);
      if (t + 3072 < n0) atomicAdd(&h[(uint32_t)(K3 >> 29)], 1u);
      if (t < ne)        atomicAdd(&h[(uint32_t)(KE >> 29)], 1u);
      __syncthreads();
      if (t < 256) {
        uint32_t s = 0;
#pragma unroll
        for (int i = 0; i < 16; ++i) s += h[t * 16 + ((i + t) & 15)];   // rotated
        S[t] = s;
      }
      __syncthreads();
      for (int st = 1; st < 256; st <<= 1) {
        uint32_t v = 0;
        if (t < 256 && t >= st) v = S[t - st];
        __syncthreads();
        if (t < 256) S[t] += v;
        __syncthreads();
      }
      if (t < 256) {
        uint32_t before = (t == 0) ? 0u : S[t - 1];
        if (S[t] >= target && before < target) {
          uint32_t acc = before;
          for (int i = 0; i < 16; ++i) {
            uint32_t c = h[t * 16 + i];
            if (acc + c >= target) { sb2 = (uint32_t)(t * 16 + i); sr2 = target - acc; break; }
            acc += c;
          }
        }
      }
      __syncthreads();
      uint32_t b2 = sb2, r2 = sr2;
#define PROCB(KK, VALID) \
      if (VALID) { \
        uint32_t bin = (uint32_t)((KK) >> 29); \
        if (bin < b2) { \
          uint32_t p = (uint32_t)(KK) & 0x3FFFFu; \
          atomicOr(&G32[p >> 5], 1u << (p & 31)); \
        } else if (bin == b2) { \
          uint32_t pos = atomicAdd(&tcnt, 1u); \
          if (pos < 1024u) tie[pos] = (KK); \
        } \
      }
      PROCB(K0, t < n0) PROCB(K1, t + 1024 < n0) PROCB(K2, t + 2048 < n0)
      PROCB(K3, t + 3072 < n0) PROCB(KE, t < ne)
#undef PROCB
      __syncthreads();
      int m = min((int)tcnt, 1024);
      int r = min((int)r2, m);
      if (t < m) {
        uint64_t mk = tie[t];
        int rank = 0;
        for (int i = 0; i < m; ++i) rank += (tie[i] < mk) ? 1 : 0;
        if (rank < r) {
          uint32_t p = (uint32_t)mk & 0x3FFFFu;
          atomicOr(&G32[p >> 5], 1u << (p & 31));
        }
      }
    }
  }
  __syncthreads();   // Gbit complete; pool(ks/ebuf) dead

  // ---------------- fg select (into Fbit) ----------------
  {
    const uint64_t* eb = bmE + (size_t)b * WPI;
    if (E <= (uint32_t)NSEED) {
      for (int i = t; i < WPI; i += 1024) Fbit[i] = eb[i];   // all eligible
      __syncthreads();
    } else {
      uint64_t* lbuf = pool;   // u64[2048]
      if (t == 0) { lcnt = 0; tcnt = 0; }
      for (int i = t; i < 4096; i += 1024) h[i] = 0;
      __syncthreads();
      float tvf = floorf((1.0f - (float)MARGIN / (float)E) * 8388608.0f);
      uint32_t T = (uint32_t)fmaxf(tvf, 0.0f);
      uint32_t k0 = keys[b * 4 + 0], k1 = keys[b * 4 + 1];
      int lane = t & 63;
      for (int k = 0; k < HW / 1024; ++k) {
        uint32_t p = (uint32_t)(k * 1024 + t);
        uint64_t wbits = eb[p >> 6];
        if ((wbits >> lane) & 1ull) {
          uint32_t v = score_bits(k0, k1, p) >> 9;
          if (v >= T) {
            uint32_t pos = atomicAdd(&lcnt, 1u);
            uint64_t key = (((uint64_t)((~v) & 0x7FFFFFu)) << 18) | p;
            if (pos < (uint32_t)LBUF) lbuf[pos] = key;
            else { uint32_t gp = atomicAdd(&cnt_fg[bsub], 1u);
                   if (gp < (uint32_t)CAP2) list_fg[(size_t)bsub * CAP2 + gp] = key; }
          }
        }
      }
      __syncthreads();
      int m2 = min((int)lcnt, LBUF);
      if (t == 0) gbase = atomicAdd(&cnt_fg[bsub], (uint32_t)m2);
      __syncthreads();
      for (int i = t; i < m2; i += 1024) {
        uint32_t pos = gbase + (uint32_t)i;
        if (pos < (uint32_t)CAP2) list_fg[(size_t)bsub * CAP2 + pos] = lbuf[i];
      }
      __syncthreads();
      int n = min((int)cnt_fg[bsub], CAP2);
      if (n > 0) {
        uint32_t target = (uint32_t)min(NSEED, n);
        const uint64_t* lb = list_fg + (size_t)bsub * CAP2;
        uint64_t K0 = (t < n)        ? lb[t]        : 0;
        uint64_t K1 = (t + 1024 < n) ? lb[t + 1024] : 0;
        uint64_t K2 = (t + 2048 < n) ? lb[t + 2048] : 0;
        uint64_t K3 = (t + 3072 < n) ? lb[t + 3072] : 0;
        if (t < n)        atomicAdd(&h[(uint32_t)(K0 >> 29)], 1u);
        if (t + 1024 < n) atomicAdd(&h[(uint32_t)(K1 >> 29)], 1u);
        if (t + 2048 < n) atomicAdd(&h[(uint32_t)(K2 >> 29)], 1u);
        if (t + 3072 < n) atomicAdd(&h[(uint32_t)(K3 >> 29)], 1u);
        __syncthreads();
        if (t < 256) {
          uint32_t s = 0;
#pragma unroll
          for (int i = 0; i < 16; ++i) s += h[t * 16 + ((i + t) & 15)];   // rotated
          S[t] = s;
        }
        __syncthreads();
        for (int st = 1; st < 256; st <<= 1) {
          uint32_t v = 0;
          if (t < 256 && t >= st) v = S[t - st];
          __syncthreads();
          if (t < 256) S[t] += v;
          __syncthreads();
        }
        if (t < 256) {
          uint32_t before = (t == 0) ? 0u : S[t - 1];
          if (S[t] >= target && before < target) {
            uint32_t acc = before;
            for (int i = 0; i < 16; ++i) {
              uint32_t c = h[t * 16 + i];
              if (acc + c >= target) { sb2 = (uint32_t)(t * 16 + i); sr2 = target - acc; break; }
              acc += c;
            }
          }
        }
        __syncthreads();
        uint32_t b2 = sb2, r2 = sr2;
#define PROCF(KK, VALID) \
        if (VALID) { \
          uint32_t bin = (uint32_t)((KK) >> 29); \
          if (bin < b2) { \
            uint32_t p = (uint32_t)(KK) & 0x3FFFFu; \
            atomicOr(&F32[p >> 5], 1u << (p & 31)); \
          } else if (bin == b2) { \
            uint32_t pos = atomicAdd(&tcnt, 1u); \
            if (pos < 1024u) tie[pos] = (KK); \
          } \
        }
        PROCF(K0, t < n) PROCF(K1, t + 1024 < n) PROCF(K2, t + 2048 < n)
        PROCF(K3, t + 3072 < n)
#undef PROCF
        __syncthreads();
        int m = min((int)tcnt, 1024);
        int r = min((int)r2, m);
        if (t < m) {
          uint64_t mk = tie[t];
          int rank = 0;
          for (int i = 0; i < m; ++i) rank += (tie[i] < mk) ? 1 : 0;
          if (rank < r) {
            uint32_t p = (uint32_t)mk & 0x3FFFFu;
            atomicOr(&F32[p >> 5], 1u << (p & 31));
          }
        }
      }
      __syncthreads();
    }
  }
  __syncthreads();   // Fbit complete; pool fully dead

  // ------- compose this block's half: 4 iters x {1024 words, 8192 int4} -----
  uint64_t* FdS = pool;          // u64[512]
  uint64_t* BdS = pool + 512;    // u64[512]
  for (int it = 0; it < 4; ++it) {
    {
      int s = t >> 7, xx = t & 127;
      int w = xx & 63;
      int rg = sub * 32 + it * 8 + s;
      int r = rg * 8 + (w >> 3), c = w & 7;
      const uint64_t* src = (xx < 64) ? Fbit : Gbit;
      uint64_t d = 0;
#pragma unroll
      for (int dr = -1; dr <= 1; ++dr) {
        int rr = r + dr;
        if (rr < 0 || rr >= H) continue;
        int wi = rr * 8 + c;
        uint64_t cur = src[wi];
        uint64_t lf = (c > 0) ? src[wi - 1] : 0ull;
        uint64_t rt = (c < 7) ? src[wi + 1] : 0ull;
        d |= cur | (cur << 1) | (lf >> 63) | (cur >> 1) | (rt << 63);
      }
      if (xx < 64) FdS[s * 64 + w] = d; else BdS[s * 64 + w] = d;
    }
    __syncthreads();
    int4* ob = (int4*)out + (size_t)b * (HW / 4) + (size_t)sub * (HW / 8)
             + (size_t)it * 8192;
#pragma unroll
    for (int k2 = 0; k2 < 8; ++k2) {
      int idx = k2 * 1024 + t;         // [0, 8192)
      int ss = idx >> 10, i = idx & 1023;
      int ww = i >> 4, sub4 = i & 15;
      uint64_t Fd = FdS[ss * 64 + ww], Bd = BdS[ss * 64 + ww];
      uint64_t ov = Fd & Bd;
      Fd &= ~ov; Bd &= ~ov;
      int sh = sub4 * 4;
      int4 o;
      o.x = ((Fd >> (sh + 0)) & 1ull) ? 1 : (((Bd >> (sh + 0)) & 1ull) ? 0 : -255);
      o.y = ((Fd >> (sh + 1)) & 1ull) ? 1 : (((Bd >> (sh + 1)) & 1ull) ? 0 : -255);
      o.z = ((Fd >> (sh + 2)) & 1ull) ? 1 : (((Bd >> (sh + 2)) & 1ull) ? 0 : -255);
      o.w = ((Fd >> (sh + 3)) & 1ull) ? 1 : (((Bd >> (sh + 3)) & 1ull) ? 0 : -255);
      ob[idx] = o;
    }
    __syncthreads();
  }
}

extern "C" void kernel_launch(void* const* d_in, const int* in_sizes, int n_in,
                              void* d_out, int out_size, void* d_ws, size_t ws_size,
                              hipStream_t stream) {
  (void)in_sizes; (void)n_in; (void)out_size; (void)ws_size;
  const float* x = (const float*)d_in[0];
  int* out = (int*)d_out;
  char* ws = (char*)d_ws;

  // g (u16 bins, 64 MB) lives in the OUTPUT buffer (128 MB): written by
  // k_binify, read only by k_main, fully overwritten by k_selcomp at the end.
  u16* g = (u16*)d_out;

  // ---- workspace layout (no host memset needed) ----
  uint32_t* keys   = (uint32_t*)(ws + 0);       // 2048
  uint32_t* kbg    = (uint32_t*)(ws + 2048);    // 512
  int*      th     = (int*)     (ws + 2560);    // 512
  uint32_t* b1a    = (uint32_t*)(ws + 3072);    // 512
  uint32_t* r1a    = (uint32_t*)(ws + 3584);
  uint32_t* Tbg    = (uint32_t*)(ws + 4096);
  uint32_t* Efg    = (uint32_t*)(ws + 4608);
  uint32_t* cnt_be = (uint32_t*)(ws + 5120);
  uint32_t* cnt_bg = (uint32_t*)(ws + 5632);
  uint32_t* cnt_fg = (uint32_t*)(ws + 6144);    // 1024 B (256 slots)
  uint32_t* gh      = (uint32_t*)(ws + 8192);                      // 8 MB
  uint64_t* list    = (uint64_t*)(ws + 8192 + 8388608);            // 4 MB (bg)
  uint64_t* list_be = (uint64_t*)(ws + 8192 + 8388608 + 4194304);  // 1 MB
  uint64_t* bmE     = (uint64_t*)(ws + 8192 + 8388608 + 5242880);  // 4 MB
  uint64_t* list_fg = (uint64_t*)gh;   // gh dead after k_otsu; 256 x CAP2 x 8B

  k_binify  <<<BATCH * 4, 1024, 0, stream>>>((const float4*)x, g, gh, keys, kbg,
                                             Tbg, Efg, cnt_fg, cnt_be, cnt_bg);
  k_otsu    <<<BATCH, 256, 0, stream>>>(gh, kbg, th, b1a, r1a);
  k_main    <<<BATCH * 4, 1024, 0, stream>>>(g, x, th, b1a, Tbg, keys,
                                             Efg, cnt_bg, list, cnt_be, list_be, bmE);
  k_selcomp <<<BATCH * 2, 1024, 0, stream>>>(r1a, cnt_be, list_be, Tbg, keys,
                                             cnt_bg, list, Efg, cnt_fg, list_fg,
                                             bmE, out);
}